// Round 6
// baseline (169.382 us; speedup 1.0000x reference)
//
#include <hip/hip_runtime.h>
#include <cmath>
#include <cstdint>

#define NB 8
#define NPROP 1000
#define NCLS 80
#define NLOG 81
#define KCAND 1024
#define NTH 10
#define DFEAT 2048
#define NOBJ 6
#define NSCORE (NPROP*NCLS)   // 80000
#define HBLK 8                // histogram/gather blocks per image
#define HCHUNK (NSCORE/HBLK)  // 10000 elements per block
#define PCHUNK (NPROP/HBLK)   // 125 proposals per block

// ---------------- workspace layout (bytes) ----------------
constexpr size_t OFF_SCORES = 0;
constexpr size_t SZ_SCORES  = (size_t)NB * NSCORE * 4;                 // 2,560,000
constexpr size_t OFF_LISTA  = OFF_SCORES + SZ_SCORES;
constexpr size_t SZ_LISTA   = (size_t)NB * 20 * KCAND * 8;             // 1,310,720 capacity
constexpr size_t OFF_H1     = OFF_LISTA;                               // 524,288
constexpr size_t OFF_H2     = OFF_H1 + (size_t)NB * HBLK * 2048 * 4;   // 524,288
constexpr size_t OFF_PIV    = OFF_H2 + (size_t)NB * HBLK * 2048 * 4;   // 256
constexpr size_t OFF_CBUF   = OFF_PIV + (size_t)NB * 8 * 4;            // 131,072
constexpr size_t OFF_CANDK  = OFF_LISTA + SZ_LISTA;
constexpr size_t SZ_CANDK   = (size_t)NB * KCAND * 8;
constexpr size_t OFF_CX1    = OFF_CANDK + SZ_CANDK;
constexpr size_t SZ_CARR    = (size_t)NB * KCAND * 4;
constexpr size_t OFF_CY1    = OFF_CX1 + SZ_CARR;
constexpr size_t OFF_CX2    = OFF_CY1 + SZ_CARR;
constexpr size_t OFF_CY2    = OFF_CX2 + SZ_CARR;
constexpr size_t OFF_CAREA  = OFF_CY2 + SZ_CARR;
constexpr size_t OFF_CPROP  = OFF_CAREA + SZ_CARR;
constexpr size_t OFF_VALIDW = OFF_CPROP + SZ_CARR;
constexpr size_t SZ_VALIDW  = (size_t)NB * 16 * 8;                     // 1024
constexpr size_t OFF_MASKS  = OFF_VALIDW + SZ_VALIDW;                  // contiguous after validw
constexpr size_t SZ_MASKS   = (size_t)NTH * NB * KCAND * 16 * 8;       // 10,485,760
constexpr size_t OFF_KEEPS  = OFF_MASKS + SZ_MASKS;
constexpr size_t SZ_KEEPS   = (size_t)NB * NTH * 16 * 8;
constexpr size_t OFF_COUNTS = OFF_KEEPS + SZ_KEEPS;
constexpr size_t SZ_COUNTS  = (size_t)NB * NTH * 4;
constexpr size_t OFF_CCLS   = OFF_COUNTS + SZ_COUNTS;
constexpr size_t SZ_CCLS    = (size_t)NB * KCAND * 4;

// per-threshold word stride in the masks array
#define TSTRIDE ((size_t)NB * 16 * 1024)

__device__ __forceinline__ float nms_th(int t) {
    // replicates float32(np.arange(0.001, 1.0, 0.1)[t])
    return (float)(0.001 + 0.1 * (double)t);
}

// monotone key: ascending u64 order == (score desc, flat idx asc) == lax.top_k order
__device__ __forceinline__ unsigned score_vkey(float v) {
    float vv = (v > 1e-4f) ? v : -1.0f;
    unsigned bits = __float_as_uint(vv);
    unsigned u = (bits & 0x80000000u) ? ~bits : (bits | 0x80000000u);  // ascending by value
    return ~u;                                                          // ascending = score desc
}

// K0: zero validw+masks (contiguous span; ws is re-poisoned 0xAA before every launch)
__global__ void k_memz(ulonglong2* __restrict__ p, int n) {
    int g = blockIdx.x * blockDim.x + threadIdx.x;
    if (g < n) p[g] = ulonglong2{0ULL, 0ULL};
}

// K1: fused softmax + scores write + level-1 histogram (vkey bits [31:21], 2048 bins)
__global__ __launch_bounds__(1024) void k_softhist(const float* __restrict__ logits,
                                                   float* __restrict__ scores,
                                                   unsigned* __restrict__ hist1) {
    __shared__ unsigned hh[2048];
    int img = blockIdx.x >> 3, blk = blockIdx.x & 7;
    int tid = threadIdx.x, wid = tid >> 6, lane = tid & 63;
    hh[tid] = 0; hh[tid + 1024] = 0;
    __syncthreads();
    for (int p = wid; p < PCHUNK; p += 16) {
        int prop = blk * PCHUNK + p;
        const float* L = logits + ((size_t)img * NPROP + prop) * NLOG;
        float l0 = L[lane];
        float l1 = (lane < 17) ? L[64 + lane] : -INFINITY;
        float m = fmaxf(l0, l1);
        #pragma unroll
        for (int o = 32; o > 0; o >>= 1) m = fmaxf(m, __shfl_xor(m, o, 64));
        float e0 = expf(l0 - m);
        float e1 = (lane < 17) ? expf(l1 - m) : 0.f;
        float s = e0 + e1;
        #pragma unroll
        for (int o = 32; o > 0; o >>= 1) s += __shfl_xor(s, o, 64);
        float* op = scores + ((size_t)img * NPROP + prop) * NCLS;
        float p0 = e0 / s;
        op[lane] = p0;
        atomicAdd(&hh[score_vkey(p0) >> 21], 1u);
        if (lane < 16) {
            float p1 = e1 / s;
            op[64 + lane] = p1;
            atomicAdd(&hh[score_vkey(p1) >> 21], 1u);
        }
    }
    __syncthreads();
    unsigned* outp = hist1 + ((size_t)img * HBLK + blk) * 2048;
    outp[tid] = hh[tid];
    outp[tid + 1024] = hh[tid + 1024];
}

// block-wide: sum 8 sub-hists, scan 2048 bins, find crossing bin for rank K.
// Results land in shared (*out_b, *out_rem); caller must __syncthreads() after.
__device__ __forceinline__ void pivot_scan(const unsigned* __restrict__ h8, unsigned K,
                                           int* __restrict__ out_b, int* __restrict__ out_rem) {
    __shared__ unsigned wsum[16];
    int tid = threadIdx.x;
    unsigned a = 0, b = 0;
    #pragma unroll
    for (int s = 0; s < HBLK; ++s) {
        a += h8[s * 2048 + 2 * tid];
        b += h8[s * 2048 + 2 * tid + 1];
    }
    unsigned p = a + b;
    unsigned x = p;
    #pragma unroll
    for (int d = 1; d < 64; d <<= 1) {
        unsigned y = __shfl_up(x, (unsigned)d, 64);
        if ((tid & 63) >= d) x += y;
    }
    if ((tid & 63) == 63) wsum[tid >> 6] = x;
    __syncthreads();
    if (tid < 16) {
        unsigned w = wsum[tid];
        #pragma unroll
        for (int d = 1; d < 16; d <<= 1) {
            unsigned y = __shfl_up(w, (unsigned)d, 64);
            if (tid >= d) w += y;
        }
        wsum[tid] = w;  // inclusive wave sums
    }
    __syncthreads();
    unsigned wex = (tid >= 64) ? wsum[(tid >> 6) - 1] : 0u;
    unsigned incl = x + wex;
    unsigned E = incl - p;
    if (E < K && E + a >= K)              { *out_b = 2 * tid;     *out_rem = (int)(K - E); }
    else if (E + a < K && E + a + b >= K) { *out_b = 2 * tid + 1; *out_rem = (int)(K - (E + a)); }
}

// K2: per-block redundant pivot1 + level-2 histogram restricted to bin b1
__global__ __launch_bounds__(1024) void k_hist2p(const float* __restrict__ scores,
                                                 const unsigned* __restrict__ hist1,
                                                 unsigned* __restrict__ hist2,
                                                 int* __restrict__ piv) {
    __shared__ unsigned hh[2048];
    __shared__ int sb, sr;
    int img = blockIdx.x >> 3, blk = blockIdx.x & 7;
    int tid = threadIdx.x;
    hh[tid] = 0; hh[tid + 1024] = 0;
    pivot_scan(hist1 + (size_t)img * HBLK * 2048, KCAND, &sb, &sr);
    __syncthreads();
    unsigned b1 = (unsigned)sb;
    const float* sc = scores + (size_t)img * NSCORE + (size_t)blk * HCHUNK;
    for (int e = tid; e < HCHUNK; e += 1024) {
        unsigned vk = score_vkey(sc[e]);
        if ((vk >> 21) == b1) atomicAdd(&hh[(vk >> 10) & 2047u], 1u);
    }
    __syncthreads();
    unsigned* outp = hist2 + ((size_t)img * HBLK + blk) * 2048;
    outp[tid] = hh[tid];
    outp[tid + 1024] = hh[tid + 1024];
    if (blk == 0 && tid == 0) {
        piv[img * 8 + 0] = sb;   // b1
        piv[img * 8 + 1] = sr;   // residual rank K2
        piv[img * 8 + 3] = 0;    // gather counter (zeroed for next kernel)
    }
}

// K3: per-block redundant pivot2 -> T22, then gather all keys with top22 <= T22
__global__ __launch_bounds__(1024) void k_gatherp(const float* __restrict__ scores,
                                                  const unsigned* __restrict__ hist2,
                                                  int* __restrict__ piv,
                                                  unsigned long long* __restrict__ cbuf) {
    __shared__ int sb2, sr2;
    __shared__ unsigned lcnt, gbase;
    int img = blockIdx.x >> 3, blk = blockIdx.x & 7;
    int tid = threadIdx.x;
    if (tid == 0) lcnt = 0;
    unsigned K2 = (unsigned)piv[img * 8 + 1];
    pivot_scan(hist2 + (size_t)img * HBLK * 2048, K2, &sb2, &sr2);
    __syncthreads();
    unsigned T22 = ((unsigned)piv[img * 8 + 0] << 11) | (unsigned)sb2;
    const float* sc = scores + (size_t)img * NSCORE + (size_t)blk * HCHUNK;
    unsigned long long sel[(HCHUNK + 1023) / 1024];
    int ns = 0;
    for (int e = tid; e < HCHUNK; e += 1024) {
        unsigned vk = score_vkey(sc[e]);
        if ((vk >> 10) <= T22)
            sel[ns++] = ((unsigned long long)vk << 32) | (unsigned)(blk * HCHUNK + e);
    }
    unsigned lp = atomicAdd(&lcnt, (unsigned)ns);
    __syncthreads();
    if (tid == 0) gbase = atomicAdd((unsigned*)&piv[img * 8 + 3], lcnt);
    __syncthreads();
    unsigned long long* ob = cbuf + (size_t)img * 2048;
    for (int i = 0; i < ns; ++i) {
        unsigned pos = gbase + lp + (unsigned)i;
        if (pos < 2048) ob[pos] = sel[i];
    }
}

// K4: rank-by-counting + candidate prep fused. Thread's key gets exact rank r
// (keys unique); r<1024 threads decode, clip, offset, compute area, and write
// candidate arrays at position r. validw bits via atomicOr (pre-zeroed).
__global__ __launch_bounds__(256) void k_rankcand(const unsigned long long* __restrict__ cbuf,
                                                  const int* __restrict__ piv,
                                                  const float* __restrict__ boxes,
                                                  const int* __restrict__ hw,
                                                  float* __restrict__ cx1, float* __restrict__ cy1,
                                                  float* __restrict__ cx2, float* __restrict__ cy2,
                                                  float* __restrict__ car, int* __restrict__ cprop,
                                                  int* __restrict__ ccls,
                                                  unsigned long long* __restrict__ validw) {
    __shared__ unsigned long long keys[2048];
    int img = blockIdx.x >> 3, sl = blockIdx.x & 7;
    int tid = threadIdx.x;
    int cnt = piv[img * 8 + 3]; if (cnt > 2048) cnt = 2048;
    const unsigned long long* ib = cbuf + (size_t)img * 2048;
    #pragma unroll
    for (int k = 0; k < 8; ++k) {
        int t = k * 256 + tid;
        keys[t] = (t < cnt) ? ib[t] : ~0ULL;
    }
    __syncthreads();
    unsigned long long a = keys[sl * 256 + tid];
    int r = 0;
    #pragma unroll 8
    for (int j = 0; j < cnt; ++j) r += (keys[j] < a) ? 1 : 0;
    if (r < KCAND) {
        unsigned u   = ~(unsigned)(a >> 32);
        unsigned idx = (unsigned)a;
        const unsigned uth = __float_as_uint(1e-4f) | 0x80000000u;
        bool valid = u > uth;
        int prop = (int)(idx / NCLS);
        int cls  = (int)(idx - (unsigned)prop * NCLS);
        const float4 bx = *(const float4*)(boxes + ((((size_t)img * NPROP + prop) * NCLS + cls) << 2));
        float h = (float)hw[img * 2 + 0];
        float w = (float)hw[img * 2 + 1];
        float x1 = fminf(fmaxf(bx.x, 0.f), w);
        float y1 = fminf(fmaxf(bx.y, 0.f), h);
        float x2 = fminf(fmaxf(bx.z, 0.f), w);
        float y2 = fminf(fmaxf(bx.w, 0.f), h);
        float offc = __fmul_rn((float)cls, 4096.0f);
        x1 = __fadd_rn(x1, offc); y1 = __fadd_rn(y1, offc);
        x2 = __fadd_rn(x2, offc); y2 = __fadd_rn(y2, offc);
        float area = __fmul_rn(__fsub_rn(x2, x1), __fsub_rn(y2, y1));
        int o = img * KCAND + r;
        cx1[o] = x1; cy1[o] = y1; cx2[o] = x2; cy2[o] = y2;
        car[o] = area; cprop[o] = prop; ccls[o] = cls;
        if (valid) atomicOr(&validw[img * 16 + (r >> 6)], 1ULL << (r & 63));
    }
}

// K5: per-row IoU -> transposed triangular suppression masks. Two gates:
// (a) class pre-gate: iou>th needs inter>0 which needs same class (offset 4096 >
//     max coord 800), checked before loading any coordinates;
// (b) inter>0 gate before the division + 10 ballots.
// Gated-out chunks store nothing (array pre-zeroed by k_memz).
__global__ void k_masks(const float* __restrict__ cx1, const float* __restrict__ cy1,
                        const float* __restrict__ cx2, const float* __restrict__ cy2,
                        const float* __restrict__ car, const int* __restrict__ ccls,
                        unsigned long long* __restrict__ masks) {
    int gw   = (blockIdx.x * blockDim.x + threadIdx.x) >> 6;  // global wave = row
    int lane = threadIdx.x & 63;
    if (gw >= NB * KCAND) return;
    int bimg = gw >> 10;
    int i    = gw & (KCAND - 1);
    int cb   = bimg * KCAND;
    int   ci  = ccls[cb + i];
    float xi1 = cx1[cb + i], yi1 = cy1[cb + i];
    float xi2 = cx2[cb + i], yi2 = cy2[cb + i], ai = car[cb + i];
    int cmax = i >> 6;
    for (int c = 0; c <= cmax; ++c) {
        int j = c * 64 + lane;
        bool jlt = j < i;
        int cj = ccls[cb + j];
        if (__ballot(jlt && (cj == ci)) == 0ULL) continue;   // cross-class chunk: all zero
        float xj1 = cx1[cb + j], yj1 = cy1[cb + j];
        float xj2 = cx2[cb + j], yj2 = cy2[cb + j], aj = car[cb + j];
        float iw = fmaxf(__fsub_rn(fminf(xi2, xj2), fmaxf(xi1, xj1)), 0.f);
        float ih = fmaxf(__fsub_rn(fminf(yi2, yj2), fmaxf(yi1, yj1)), 0.f);
        float inter = __fmul_rn(iw, ih);
        if (__ballot(jlt && (inter > 0.f)) == 0ULL) continue;  // all 10 masks zero
        float uni = __fsub_rn(__fadd_rn(ai, aj), inter);
        float iou = (uni > 0.f) ? __fdiv_rn(inter, uni) : 0.f;
        unsigned long long bl[NTH];
        #pragma unroll
        for (int t = 0; t < NTH; ++t) bl[t] = __ballot(jlt && (iou > nms_th(t)));
        unsigned long long myv = 0;
        #pragma unroll
        for (int t = 0; t < NTH; ++t) myv = (lane == t) ? bl[t] : myv;
        if (lane < NTH)
            masks[(size_t)lane * TSTRIDE + (((size_t)(bimg * 16 + c)) << 10) + i] = myv;
    }
}

// K6: greedy NMS via Jacobi fixed-point iteration (exact greedy fixed point).
__global__ __launch_bounds__(1024) void k_scan(const unsigned long long* __restrict__ masks,
                                               const unsigned long long* __restrict__ validw,
                                               unsigned long long* __restrict__ keeps,
                                               int* __restrict__ counts) {
    __shared__ unsigned long long kp[16];
    __shared__ int changed[2];
    int bt   = blockIdx.x;
    int bimg = bt / NTH, t = bt % NTH;
    int tid  = threadIdx.x;
    int w    = tid >> 6;
    int lane = tid & 63;
    const unsigned long long* mb = masks + (size_t)t * TSTRIDE + ((size_t)(bimg * 16) << 10);
    unsigned long long row[16];
    #pragma unroll
    for (int c = 0; c < 16; ++c)
        row[c] = (c <= w) ? mb[((size_t)c << 10) + tid] : 0ULL;
    unsigned long long vw = validw[bimg * 16 + w];
    bool valid = (vw >> lane) & 1ULL;
    if (tid < 16) kp[tid] = validw[bimg * 16 + tid];
    if (tid < 2) changed[tid] = 0;
    __syncthreads();
    for (int iter = 0; iter < KCAND + 2; ++iter) {
        unsigned long long s = 0;
        #pragma unroll
        for (int c = 0; c < 16; ++c) s |= row[c] & kp[c];
        bool nk = valid && (s == 0);
        unsigned long long bal = __ballot(nk);
        bool diff = (lane == 0) && (bal != kp[w]);
        __syncthreads();
        if (diff) { kp[w] = bal; changed[iter & 1] = 1; }
        if (tid == 0) changed[(iter + 1) & 1] = 0;
        __syncthreads();
        if (!changed[iter & 1]) break;
    }
    if (tid < 16) keeps[((size_t)bimg * NTH + t) * 16 + tid] = kp[tid];
    if (tid < 64) {
        int c = (lane < 16) ? __popcll(kp[lane]) : 0;
        #pragma unroll
        for (int o = 32; o > 0; o >>= 1) c += __shfl_xor(c, o, 64);
        if (lane == 0) counts[bimg * NTH + t] = c;
    }
}

// K7: fused threshold-select + top-6 id walk + transposed feature gather.
// Each block (img, 256-d-slice) redoes the tiny selection from LDS-staged words.
__global__ __launch_bounds__(256) void k_selfeat(const int* __restrict__ counts,
                                                 const unsigned long long* __restrict__ keeps,
                                                 const int* __restrict__ cprop,
                                                 const float* __restrict__ feats,
                                                 float* __restrict__ outp) {
    __shared__ int scnt[NTH];
    __shared__ unsigned long long skw[16];
    __shared__ int stsel;
    __shared__ int sids[NOBJ];
    int img = blockIdx.x >> 3;
    int tid = threadIdx.x;
    if (tid < NTH) scnt[tid] = counts[img * NTH + tid];
    __syncthreads();
    if (tid == 0) {
        int tsel = NTH - 1;
        for (int t = 0; t < NTH; ++t) if (scnt[t] >= NOBJ) { tsel = t; break; }
        stsel = tsel;
    }
    __syncthreads();
    if (tid < 16) skw[tid] = keeps[((size_t)img * NTH + stsel) * 16 + tid];
    __syncthreads();
    if (tid == 0) {
        int got = 0;
        for (int k = 0; k < 16 && got < NOBJ; ++k) {
            unsigned long long x = skw[k];
            while (x && got < NOBJ) {
                int b = __builtin_ctzll(x);
                sids[got++] = cprop[img * KCAND + k * 64 + b];
                x &= x - 1;
            }
        }
        for (int k = 0; k < 16 && got < NOBJ; ++k) {
            unsigned long long x = ~skw[k];
            while (x && got < NOBJ) {
                int b = __builtin_ctzll(x);
                sids[got++] = cprop[img * KCAND + k * 64 + b];
                x &= x - 1;
            }
        }
    }
    __syncthreads();
    int d = (blockIdx.x & 7) * 256 + tid;
    const float* fb = feats + (size_t)img * NPROP * DFEAT;
    float* ob = outp + ((size_t)img * DFEAT + d) * NOBJ;
    #pragma unroll
    for (int s = 0; s < NOBJ; ++s)
        ob[s] = fb[(size_t)sids[s] * DFEAT + d];
}

extern "C" void kernel_launch(void* const* d_in, const int* in_sizes, int n_in,
                              void* d_out, int out_size, void* d_ws, size_t ws_size,
                              hipStream_t stream) {
    const float* logits = (const float*)d_in[0];
    const float* boxes  = (const float*)d_in[1];
    const float* feats  = (const float*)d_in[2];
    const int*   hw     = (const int*)d_in[3];
    float* outp = (float*)d_out;

    char* ws = (char*)d_ws;
    float*              scores = (float*)(ws + OFF_SCORES);
    unsigned*           hist1  = (unsigned*)(ws + OFF_H1);
    unsigned*           hist2  = (unsigned*)(ws + OFF_H2);
    int*                piv    = (int*)(ws + OFF_PIV);
    unsigned long long* cbuf   = (unsigned long long*)(ws + OFF_CBUF);
    float* cx1 = (float*)(ws + OFF_CX1);
    float* cy1 = (float*)(ws + OFF_CY1);
    float* cx2 = (float*)(ws + OFF_CX2);
    float* cy2 = (float*)(ws + OFF_CY2);
    float* car = (float*)(ws + OFF_CAREA);
    int*   cprop = (int*)(ws + OFF_CPROP);
    int*   ccls  = (int*)(ws + OFF_CCLS);
    unsigned long long* validw = (unsigned long long*)(ws + OFF_VALIDW);
    unsigned long long* masks  = (unsigned long long*)(ws + OFF_MASKS);
    unsigned long long* keeps  = (unsigned long long*)(ws + OFF_KEEPS);
    int* counts = (int*)(ws + OFF_COUNTS);

    const int mz_n = (int)((SZ_VALIDW + SZ_MASKS) / 16);  // ulonglong2 count, validw..masks contiguous
    k_memz<<<(mz_n + 255) / 256, 256, 0, stream>>>((ulonglong2*)(ws + OFF_VALIDW), mz_n);
    k_softhist<<<NB * HBLK, 1024, 0, stream>>>(logits, scores, hist1);
    k_hist2p<<<NB * HBLK, 1024, 0, stream>>>(scores, hist1, hist2, piv);
    k_gatherp<<<NB * HBLK, 1024, 0, stream>>>(scores, hist2, piv, cbuf);
    k_rankcand<<<NB * HBLK, 256, 0, stream>>>(cbuf, piv, boxes, hw,
                                              cx1, cy1, cx2, cy2, car, cprop, ccls, validw);
    k_masks<<<(NB * KCAND) / 4, 256, 0, stream>>>(cx1, cy1, cx2, cy2, car, ccls, masks);
    k_scan<<<NB * NTH, 1024, 0, stream>>>(masks, validw, keeps, counts);
    k_selfeat<<<NB * HBLK, 256, 0, stream>>>(counts, keeps, cprop, feats, outp);
}